// Round 5
// baseline (386.385 us; speedup 1.0000x reference)
//
#include <hip/hip_runtime.h>
#include <cstdint>
#include <cstddef>

// B=1024 batches, P=64 patches, C=512 channels. res = X + MLP_patch(X), then LN over C.
#define BB 1024
#define PP 64
#define CC 512
constexpr float LN_EPS = 1e-5f;

typedef short  s16x8 __attribute__((ext_vector_type(8)));
typedef float  f32x4 __attribute__((ext_vector_type(4)));
typedef unsigned int u32x2 __attribute__((ext_vector_type(2)));

__device__ __forceinline__ unsigned cvt_pk_bf16(float lo, float hi) {
    unsigned r;
    asm("v_cvt_pk_bf16_f32 %0, %1, %2" : "=v"(r) : "v"(lo), "v"(hi));  // RNE on gfx950
    return r;
}
__device__ __forceinline__ float bflo(unsigned u) { union { unsigned u; float f; } v; v.u = u << 16;          return v.f; }
__device__ __forceinline__ float bfhi(unsigned u) { union { unsigned u; float f; } v; v.u = u & 0xffff0000u;  return v.f; }

__device__ __forceinline__ s16x8 ldwf(const float* p) {
    float4 a = *(const float4*)p;
    float4 b = *(const float4*)(p + 4);
    union { s16x8 v; unsigned u[4]; } r;
    r.u[0] = cvt_pk_bf16(a.x, a.y);
    r.u[1] = cvt_pk_bf16(a.z, a.w);
    r.u[2] = cvt_pk_bf16(b.x, b.y);
    r.u[3] = cvt_pk_bf16(b.z, b.w);
    return r.v;
}

__device__ __forceinline__ float gelu_t(float t) {
    float sg = 1.5957691216f * (t + 0.044715f * t * t * t);
    return t / (1.0f + __expf(-sg));
}

// Raw barrier: LDS-handoff only. NEVER drains vmcnt (the R2->R3 lever: __syncthreads'
// implicit vmcnt(0) serialized the prefetch burst and the dead store drain each subtile).
__device__ __forceinline__ void lds_barrier() {
    asm volatile("s_waitcnt lgkmcnt(0)" ::: "memory");
    __builtin_amdgcn_s_barrier();
}

// R3: 512-thread blocks (8 waves = 8 channels), 2 blocks/CU (two independent barrier
// domains per CU overlap each other's stalls). Counted waits only: compiler inserts
// vmcnt(N) before staged-reg use; stores are never waited on inside the loop. c-pair
// blocks (h=0/1 of a 16-ch line group) are placed 8 gids apart -> same XCD (gid%8),
// so the 32-B granules of both halves merge in that XCD's L2.
__global__ __launch_bounds__(512, 4) void k_mix(
    const float* __restrict__ X,  const float* __restrict__ W1,
    const float* __restrict__ B1, const float* __restrict__ W2,
    const float* __restrict__ B2, float* __restrict__ OUT)
{
    // XS: bf16 [8 c-planes][16 b][64 p pad->72], plane stride 1160 shorts (580 words
    // ≡ 4 mod 32: staging writes 2-way, frag reads conflict-free 8-pass).
    // HS: wave-private planes, stride 1152 shorts. RS: fp32 [16 b][8 c][68 q],
    // b-stride 548 words ≡ 4 mod 32 (b128 writes 8-pass, gather reads 2-way).
    __shared__ __align__(16) unsigned short XS[8 * 1160];   // 18560 B
    __shared__ __align__(16) unsigned short HS[8 * 1152];   // 18432 B
    __shared__ __align__(16) float          RS[16 * 548];   // 35072 B  => 72 KB total

    const int tid  = threadIdx.x;
    const int lane = tid & 63;
    const int wv   = tid >> 6;        // wave -> channel offset (0..7)
    const int lb   = lane & 15;       // acc col: b-index
    const int lq   = lane >> 4;       // k-quad / acc row-quad

    const int gid = blockIdx.x;
    const int bt  = gid >> 6;         // 0..7 b-tile
    const int u   = gid & 63;
    const int xcd = u & 7;            // XCD (gid%8 heuristic)
    const int h   = (u >> 3) & 1;     // which half of the 16-ch pair
    const int cgp = xcd + (u >> 4) * 8;            // 0..31 pair group
    const int c0  = cgp * 16 + h * 8, b0 = bt * 128;
    const int c   = c0 + wv;

    // ---- W1/W2 fragments resident in regs for the whole block (A-operand) ----
    const float* w1c = W1 + (size_t)c * 4096;
    const float* w2c = W2 + (size_t)c * 4096;
    const int wq = lb * 64 + lq * 8;    // W[c][q=mt*16+lb][p=ks*32+lq*8+j]
    s16x8 w1_0_0 = ldwf(w1c +    0 + wq), w1_0_1 = ldwf(w1c +    0 + wq + 32);
    s16x8 w1_1_0 = ldwf(w1c + 1024 + wq), w1_1_1 = ldwf(w1c + 1024 + wq + 32);
    s16x8 w1_2_0 = ldwf(w1c + 2048 + wq), w1_2_1 = ldwf(w1c + 2048 + wq + 32);
    s16x8 w1_3_0 = ldwf(w1c + 3072 + wq), w1_3_1 = ldwf(w1c + 3072 + wq + 32);
    s16x8 w2_0_0 = ldwf(w2c +    0 + wq), w2_0_1 = ldwf(w2c +    0 + wq + 32);
    s16x8 w2_1_0 = ldwf(w2c + 1024 + wq), w2_1_1 = ldwf(w2c + 1024 + wq + 32);
    s16x8 w2_2_0 = ldwf(w2c + 2048 + wq), w2_2_1 = ldwf(w2c + 2048 + wq + 32);
    s16x8 w2_3_0 = ldwf(w2c + 3072 + wq), w2_3_1 = ldwf(w2c + 3072 + wq + 32);
    // biases in regs (acc rows are q = mt*16 + lq*4 + r)
    const float4 b1_0 = *(const float4*)(B1 + c * 64 +  0 + lq * 4);
    const float4 b1_1 = *(const float4*)(B1 + c * 64 + 16 + lq * 4);
    const float4 b1_2 = *(const float4*)(B1 + c * 64 + 32 + lq * 4);
    const float4 b1_3 = *(const float4*)(B1 + c * 64 + 48 + lq * 4);
    const float4 b2_0 = *(const float4*)(B2 + c * 64 +  0 + lq * 4);
    const float4 b2_1 = *(const float4*)(B2 + c * 64 + 16 + lq * 4);
    const float4 b2_2 = *(const float4*)(B2 + c * 64 + 32 + lq * 4);
    const float4 b2_3 = *(const float4*)(B2 + c * 64 + 48 + lq * 4);

    const unsigned short* xp = &XS[wv * 1160];
    unsigned short*       hp = &HS[wv * 1152];

    // staging mapping: task = (b, p-pair, c-quad); lane pairs cover 32-B row chunks
    const int sc4 = tid & 1;            // c-quad within the 8-channel slice
    const int sp2 = (tid >> 1) & 31;    // p-pair
    const int sbo = tid >> 6;           // b offset (0..7); + pass*8

    // ---- prologue: issue subtile-0 X loads into regs ----
    float4 r0[2], r1[2];
    #pragma unroll
    for (int pass = 0; pass < 2; ++pass) {
        const float* src = X + ((size_t)(b0 + pass * 8 + sbo) * PP + 2 * sp2) * CC
                             + c0 + sc4 * 4;
        r0[pass] = *(const float4*)src;
        r1[pass] = *(const float4*)(src + CC);
    }

    for (int s = 0; s < 8; ++s) {
        const int bb = b0 + s * 16;

        // ---- stage regs -> XS bf16 (transpose); compiler emits counted vmcnt here ----
        #pragma unroll
        for (int pass = 0; pass < 2; ++pass) {
            int b = pass * 8 + sbo;
            *(unsigned*)&XS[(sc4 * 4 + 0) * 1160 + b * 72 + 2 * sp2] = cvt_pk_bf16(r0[pass].x, r1[pass].x);
            *(unsigned*)&XS[(sc4 * 4 + 1) * 1160 + b * 72 + 2 * sp2] = cvt_pk_bf16(r0[pass].y, r1[pass].y);
            *(unsigned*)&XS[(sc4 * 4 + 2) * 1160 + b * 72 + 2 * sp2] = cvt_pk_bf16(r0[pass].z, r1[pass].z);
            *(unsigned*)&XS[(sc4 * 4 + 3) * 1160 + b * 72 + 2 * sp2] = cvt_pk_bf16(r0[pass].w, r1[pass].w);
        }

        // ---- issue next subtile's loads NOW (after last r use, before B1):
        //      cover = B1 + GEMM1 + GEMM2 + gather + next stage-top ----
        if (s < 7) {
            #pragma unroll
            for (int pass = 0; pass < 2; ++pass) {
                const float* src = X + ((size_t)(bb + 16 + pass * 8 + sbo) * PP + 2 * sp2) * CC
                                     + c0 + sc4 * 4;
                r0[pass] = *(const float4*)src;
                r1[pass] = *(const float4*)(src + CC);
            }
        }
        lds_barrier();                                     // B1: XS handoff (no vm drain)

        // ---- X fragments (B-operand): lane holds X[b=lb][p=lq*8+j (+32)] ----
        s16x8 xf0 = *(const s16x8*)(xp + lb * 72 +  0 + lq * 8);
        s16x8 xf1 = *(const s16x8*)(xp + lb * 72 + 32 + lq * 8);

        // ---- GEMM1 swapped: acc = W1 x X -> lane (b=lb, q=mt*16+lq*4+r); GELU ----
        #define DO1(mt) { \
            f32x4 a = {b1_##mt.x, b1_##mt.y, b1_##mt.z, b1_##mt.w}; \
            a = __builtin_amdgcn_mfma_f32_16x16x32_bf16(w1_##mt##_0, xf0, a, 0, 0, 0); \
            a = __builtin_amdgcn_mfma_f32_16x16x32_bf16(w1_##mt##_1, xf1, a, 0, 0, 0); \
            u32x2 hpk; \
            hpk[0] = cvt_pk_bf16(gelu_t(a[0]), gelu_t(a[1])); \
            hpk[1] = cvt_pk_bf16(gelu_t(a[2]), gelu_t(a[3])); \
            *(u32x2*)(hp + lb * 72 + mt * 16 + lq * 4) = hpk; }   /* ds_write_b64 */
        DO1(0) DO1(1) DO1(2) DO1(3)
        #undef DO1

        // residual reads (depend only on XS, stable since B1) issued before the drain
        u32x2 xv0 = *(const u32x2*)(xp + lb * 72 +  0 + lq * 4);
        u32x2 xv1 = *(const u32x2*)(xp + lb * 72 + 16 + lq * 4);
        u32x2 xv2 = *(const u32x2*)(xp + lb * 72 + 32 + lq * 4);
        u32x2 xv3 = *(const u32x2*)(xp + lb * 72 + 48 + lq * 4);

        // HS plane is wave-private: drain DS ops instead of a block barrier.
        asm volatile("s_waitcnt lgkmcnt(0)" ::: "memory");

        // ---- H fragments (B-operand) ----
        s16x8 hf0 = *(const s16x8*)(hp + lb * 72 +  0 + lq * 8);
        s16x8 hf1 = *(const s16x8*)(hp + lb * 72 + 32 + lq * 8);

        // ---- GEMM2 swapped + bias + residual -> RS [b][c][q] (b128 write) ----
        #define DO2(mt) { \
            f32x4 a = {b2_##mt.x, b2_##mt.y, b2_##mt.z, b2_##mt.w}; \
            a = __builtin_amdgcn_mfma_f32_16x16x32_bf16(w2_##mt##_0, hf0, a, 0, 0, 0); \
            a = __builtin_amdgcn_mfma_f32_16x16x32_bf16(w2_##mt##_1, hf1, a, 0, 0, 0); \
            a[0] += bflo(xv##mt[0]); a[1] += bfhi(xv##mt[0]); \
            a[2] += bflo(xv##mt[1]); a[3] += bfhi(xv##mt[1]); \
            *(f32x4*)&RS[lb * 548 + wv * 68 + mt * 16 + lq * 4] = a; }
        DO2(0) DO2(1) DO2(2) DO2(3)
        #undef DO2
        lds_barrier();                                     // B2: RS handoff (no vm drain)

        // ---- gather RS -> 32-B-dense stores (lane pairs cover a row's 8 channels) ----
        // Stores are never waited on inside the loop (nothing reads OUT here).
        #pragma unroll
        for (int it = 0; it < 4; ++it) {
            int fi = it * 512 + tid;          // (b, q, c-quad): 16*64*2 = 2048 tasks
            int c4 = fi & 1, q = (fi >> 1) & 63, b = fi >> 7;
            const float* rp = &RS[b * 548 + c4 * 272 + q];
            float4 v = { rp[0], rp[68], rp[136], rp[204] };
            *(float4*)(OUT + ((size_t)(bb + b) * PP + q) * CC + c0 + c4 * 4) = v;
        }
        // next iteration's B1 (lgkm0+barrier) orders gather reads vs. RS rewrites
    }
}

// LayerNorm over channels: one wave per (b,p) row (512 ch = 64 lanes x 2 float4).
__global__ __launch_bounds__(256) void k_ln(
    float* __restrict__ OUT, const float* __restrict__ G, const float* __restrict__ Be)
{
    const int lane = threadIdx.x & 63;
    const int m    = blockIdx.x * 4 + (threadIdx.x >> 6);
    float4* row = (float4*)(OUT + (size_t)m * CC);
    float4 v0 = row[lane], v1 = row[lane + 64];
    float s = (v0.x + v0.y) + (v0.z + v0.w) + (v1.x + v1.y) + (v1.z + v1.w);
    float q = (v0.x * v0.x + v0.y * v0.y) + (v0.z * v0.z + v0.w * v0.w)
            + (v1.x * v1.x + v1.y * v1.y) + (v1.z * v1.z + v1.w * v1.w);
    #pragma unroll
    for (int o = 32; o >= 1; o >>= 1) {
        s += __shfl_xor(s, o, 64);
        q += __shfl_xor(q, o, 64);
    }
    const float mu  = s * (1.0f / CC);
    const float var = q * (1.0f / CC) - mu * mu;
    const float inv = rsqrtf(var + LN_EPS);
    const float4 g0 = ((const float4*)G)[lane],  g1 = ((const float4*)G)[lane + 64];
    const float4 e0 = ((const float4*)Be)[lane], e1 = ((const float4*)Be)[lane + 64];
    v0.x = (v0.x - mu) * inv * g0.x + e0.x;  v0.y = (v0.y - mu) * inv * g0.y + e0.y;
    v0.z = (v0.z - mu) * inv * g0.z + e0.z;  v0.w = (v0.w - mu) * inv * g0.w + e0.w;
    v1.x = (v1.x - mu) * inv * g1.x + e1.x;  v1.y = (v1.y - mu) * inv * g1.y + e1.y;
    v1.z = (v1.z - mu) * inv * g1.z + e1.z;  v1.w = (v1.w - mu) * inv * g1.w + e1.w;
    row[lane] = v0; row[lane + 64] = v1;
}

extern "C" void kernel_launch(void* const* d_in, const int* in_sizes, int n_in,
                              void* d_out, int out_size, void* d_ws, size_t ws_size,
                              hipStream_t stream) {
    const float* X  = (const float*)d_in[0];
    const float* W1 = (const float*)d_in[1];
    const float* B1 = (const float*)d_in[2];
    const float* W2 = (const float*)d_in[3];
    const float* B2 = (const float*)d_in[4];
    const float* G  = (const float*)d_in[5];
    const float* Be = (const float*)d_in[6];
    float* OUT = (float*)d_out;

    k_mix<<<512, 512, 0, stream>>>(X, W1, B1, W2, B2, OUT);        // 64 c-slices x 8 b-tiles
    k_ln<<<(BB * PP) / 4, 256, 0, stream>>>(OUT, G, Be);           // 65536 rows / 4
}

// Round 6
// 339.855 us; speedup vs baseline: 1.1369x; 1.1369x over previous
//
#include <hip/hip_runtime.h>
#include <cstdint>
#include <cstddef>

// B=1024 batches, P=64 patches, C=512 channels. res = X + MLP_patch(X), then LN over C.
#define BB 1024
#define PP 64
#define CC 512
#define MM (BB * PP)            // 65536 flattened (b,p) rows
constexpr float LN_EPS = 1e-5f;

typedef short  s16x8 __attribute__((ext_vector_type(8)));
typedef float  f32x4 __attribute__((ext_vector_type(4)));
typedef unsigned int u32x2 __attribute__((ext_vector_type(2)));

__device__ __forceinline__ unsigned cvt_pk_bf16(float lo, float hi) {
    unsigned r;
    asm("v_cvt_pk_bf16_f32 %0, %1, %2" : "=v"(r) : "v"(lo), "v"(hi));  // RNE on gfx950
    return r;
}
__device__ __forceinline__ unsigned cvt_pk_f16(float lo, float hi) {
    unsigned r;
    asm("v_cvt_pkrtz_f16_f32 %0, %1, %2" : "=v"(r) : "v"(lo), "v"(hi));
    return r;
}
__device__ __forceinline__ float h2f(unsigned short h) {
    float f;
    asm("v_cvt_f32_f16 %0, %1" : "=v"(f) : "v"((unsigned)h));
    return f;
}
__device__ __forceinline__ float bflo(unsigned u) { union { unsigned u; float f; } v; v.u = u << 16;          return v.f; }
__device__ __forceinline__ float bfhi(unsigned u) { union { unsigned u; float f; } v; v.u = u & 0xffff0000u;  return v.f; }

__device__ __forceinline__ s16x8 ldwf(const float* p) {
    float4 a = *(const float4*)p;
    float4 b = *(const float4*)(p + 4);
    union { s16x8 v; unsigned u[4]; } r;
    r.u[0] = cvt_pk_bf16(a.x, a.y);
    r.u[1] = cvt_pk_bf16(a.z, a.w);
    r.u[2] = cvt_pk_bf16(b.x, b.y);
    r.u[3] = cvt_pk_bf16(b.z, b.w);
    return r.v;
}

__device__ __forceinline__ float gelu_t(float t) {
    float sg = 1.5957691216f * (t + 0.044715f * t * t * t);
    return t / (1.0f + __expf(-sg));
}

// Raw barrier: LDS-handoff only, never drains vmcnt (stores/prefetch stay in flight).
__device__ __forceinline__ void lds_barrier() {
    asm volatile("s_waitcnt lgkmcnt(0)" ::: "memory");
    __builtin_amdgcn_s_barrier();
}

// =====================================================================================
// R6 k_mix: 1024 thr = 16 waves = 16 channels (64-B X read granule, the R2 optimum).
// Acc layout (swapped MFMA) holds 4 consecutive q per f32x4 -> res is stored DIRECTLY
// per-lane to RT[c][b*64+p] in 4-KB contiguous runs per (wave, subtile): no RS gather,
// no second LDS handoff. RT is fp16 or fp32 (template), chosen by ws_size at launch.
// X reads stay strided-64B (known ~2.45 TB/s regime); write side is now stream-friendly.
// =====================================================================================
template<int HALF>
__global__ __launch_bounds__(1024, 4) void k_mix_rt(
    const float* __restrict__ X,  const float* __restrict__ W1,
    const float* __restrict__ B1, const float* __restrict__ W2,
    const float* __restrict__ B2, void* __restrict__ RTv)
{
    // XS: bf16 [16 c-planes][16 b][64 p pad->72], plane stride 1160 shorts (580 words
    // ≡ 4 mod 32: staging writes 2-way, frag reads conflict-free). HS: wave-private.
    __shared__ __align__(16) unsigned short XS[16 * 1160];   // 37120 B
    __shared__ __align__(16) unsigned short HS[16 * 1152];   // 36864 B
    __shared__ __align__(16) float          BS[16 * 128];    //  8192 B (biases)

    const int tid  = threadIdx.x;
    const int lane = tid & 63;
    const int wv   = tid >> 6;        // wave -> channel offset (0..15)
    const int lb   = lane & 15;       // acc col: b-index
    const int lq   = lane >> 4;       // k-quad / acc row-quad

    const int gid = blockIdx.x;
    const int cg  = gid & 31;         // c-group: XCD = gid%8 = cg%8 (weights L2-pinned)
    const int bt  = gid >> 5;         // 0..7 b-tile
    const int c0  = cg * 16, b0 = bt * 128;
    const int c   = c0 + wv;

    // ---- W1/W2 fragments resident for the whole block (A-operand) ----
    const float* w1c = W1 + (size_t)c * 4096;
    const float* w2c = W2 + (size_t)c * 4096;
    const int wq = lb * 64 + lq * 8;    // W[c][q=mt*16+lb][p=ks*32+lq*8+j]
    s16x8 w1_0_0 = ldwf(w1c +    0 + wq), w1_0_1 = ldwf(w1c +    0 + wq + 32);
    s16x8 w1_1_0 = ldwf(w1c + 1024 + wq), w1_1_1 = ldwf(w1c + 1024 + wq + 32);
    s16x8 w1_2_0 = ldwf(w1c + 2048 + wq), w1_2_1 = ldwf(w1c + 2048 + wq + 32);
    s16x8 w1_3_0 = ldwf(w1c + 3072 + wq), w1_3_1 = ldwf(w1c + 3072 + wq + 32);
    s16x8 w2_0_0 = ldwf(w2c +    0 + wq), w2_0_1 = ldwf(w2c +    0 + wq + 32);
    s16x8 w2_1_0 = ldwf(w2c + 1024 + wq), w2_1_1 = ldwf(w2c + 1024 + wq + 32);
    s16x8 w2_2_0 = ldwf(w2c + 2048 + wq), w2_2_1 = ldwf(w2c + 2048 + wq + 32);
    s16x8 w2_3_0 = ldwf(w2c + 3072 + wq), w2_3_1 = ldwf(w2c + 3072 + wq + 32);

    // biases -> LDS (keeps VGPR down; broadcast reads)
    BS[wv * 128 +      lane] = B1[c * 64 + lane];
    BS[wv * 128 + 64 + lane] = B2[c * 64 + lane];

    const unsigned short* xp = &XS[wv * 1160];
    unsigned short*       hp = &HS[wv * 1152];

    // staging mapping: task = (b, p-pair, c-quad); lanes 0..3 cover one 64-B row chunk
    const int sc4 = tid & 3;            // c-quad within the 16-channel slice
    const int sp2 = (tid >> 2) & 31;    // p-pair
    const int sbo = tid >> 7;           // b offset (0..7); + pass*8

    // ---- prologue: issue subtile-0 X loads into regs ----
    float4 r0[2], r1[2];
    #pragma unroll
    for (int pass = 0; pass < 2; ++pass) {
        const float* src = X + ((size_t)(b0 + pass * 8 + sbo) * PP + 2 * sp2) * CC
                             + c0 + sc4 * 4;
        r0[pass] = *(const float4*)src;
        r1[pass] = *(const float4*)(src + CC);
    }

    for (int s = 0; s < 8; ++s) {
        const int bb = b0 + s * 16;

        // ---- stage regs -> XS bf16 (transpose); compiler inserts counted vmcnt ----
        #pragma unroll
        for (int pass = 0; pass < 2; ++pass) {
            int b = pass * 8 + sbo;
            *(unsigned*)&XS[(sc4 * 4 + 0) * 1160 + b * 72 + 2 * sp2] = cvt_pk_bf16(r0[pass].x, r1[pass].x);
            *(unsigned*)&XS[(sc4 * 4 + 1) * 1160 + b * 72 + 2 * sp2] = cvt_pk_bf16(r0[pass].y, r1[pass].y);
            *(unsigned*)&XS[(sc4 * 4 + 2) * 1160 + b * 72 + 2 * sp2] = cvt_pk_bf16(r0[pass].z, r1[pass].z);
            *(unsigned*)&XS[(sc4 * 4 + 3) * 1160 + b * 72 + 2 * sp2] = cvt_pk_bf16(r0[pass].w, r1[pass].w);
        }

        // ---- issue next subtile's loads before B1: full-subtile latency cover ----
        if (s < 7) {
            #pragma unroll
            for (int pass = 0; pass < 2; ++pass) {
                const float* src = X + ((size_t)(bb + 16 + pass * 8 + sbo) * PP + 2 * sp2) * CC
                                     + c0 + sc4 * 4;
                r0[pass] = *(const float4*)src;
                r1[pass] = *(const float4*)(src + CC);
            }
        }
        lds_barrier();                                     // B1: XS (+first-iter BS) handoff

        // ---- X fragments (B-operand): lane holds X[b=lb][p=lq*8+j (+32)] ----
        s16x8 xf0 = *(const s16x8*)(xp + lb * 72 +  0 + lq * 8);
        s16x8 xf1 = *(const s16x8*)(xp + lb * 72 + 32 + lq * 8);

        // ---- GEMM1 swapped: acc = W1 x X -> lane (b=lb, q=mt*16+lq*4+r); GELU ----
        #define DO1(mt) { \
            float4 bv = *(const float4*)&BS[wv * 128 + mt * 16 + lq * 4]; \
            f32x4 a = {bv.x, bv.y, bv.z, bv.w}; \
            a = __builtin_amdgcn_mfma_f32_16x16x32_bf16(w1_##mt##_0, xf0, a, 0, 0, 0); \
            a = __builtin_amdgcn_mfma_f32_16x16x32_bf16(w1_##mt##_1, xf1, a, 0, 0, 0); \
            u32x2 hpk; \
            hpk[0] = cvt_pk_bf16(gelu_t(a[0]), gelu_t(a[1])); \
            hpk[1] = cvt_pk_bf16(gelu_t(a[2]), gelu_t(a[3])); \
            *(u32x2*)(hp + lb * 72 + mt * 16 + lq * 4) = hpk; }   /* ds_write_b64 */
        DO1(0) DO1(1) DO1(2) DO1(3)
        #undef DO1

        // residual reads (wave-local XS plane, stable since B1)
        u32x2 xv0 = *(const u32x2*)(xp + lb * 72 +  0 + lq * 4);
        u32x2 xv1 = *(const u32x2*)(xp + lb * 72 + 16 + lq * 4);
        u32x2 xv2 = *(const u32x2*)(xp + lb * 72 + 32 + lq * 4);
        u32x2 xv3 = *(const u32x2*)(xp + lb * 72 + 48 + lq * 4);

        // HS plane is wave-private: DS drain only, no block barrier.
        asm volatile("s_waitcnt lgkmcnt(0)" ::: "memory");

        // ---- H fragments (B-operand) ----
        s16x8 hf0 = *(const s16x8*)(hp + lb * 72 +  0 + lq * 8);
        s16x8 hf1 = *(const s16x8*)(hp + lb * 72 + 32 + lq * 8);

        // ---- GEMM2 + bias + residual -> DIRECT store to RT[c][(bb+lb)*64 + q] ----
        // Per instr: 16 b-rows x (4 lq x 16 B) = 64-B segments; 4 mt's tile a 4-KB run.
        const size_t rbase = (size_t)c * MM + (size_t)(bb + lb) * 64 + lq * 4;
        #define DO2(mt) { \
            float4 bv = *(const float4*)&BS[wv * 128 + 64 + mt * 16 + lq * 4]; \
            f32x4 a = {bv.x, bv.y, bv.z, bv.w}; \
            a = __builtin_amdgcn_mfma_f32_16x16x32_bf16(w2_##mt##_0, hf0, a, 0, 0, 0); \
            a = __builtin_amdgcn_mfma_f32_16x16x32_bf16(w2_##mt##_1, hf1, a, 0, 0, 0); \
            a[0] += bflo(xv##mt[0]); a[1] += bfhi(xv##mt[0]); \
            a[2] += bflo(xv##mt[1]); a[3] += bfhi(xv##mt[1]); \
            if constexpr (!HALF) { \
                *(f32x4*)((float*)RTv + rbase + mt * 16) = a; \
            } else { \
                u32x2 hv; \
                hv[0] = cvt_pk_f16(a[0], a[1]); \
                hv[1] = cvt_pk_f16(a[2], a[3]); \
                *(u32x2*)((unsigned short*)RTv + rbase + mt * 16) = hv; \
            } }
        DO2(0) DO2(1) DO2(2) DO2(3)
        #undef DO2

        lds_barrier();          // B2: all XS reads done before next subtile's staging
    }
}

// =====================================================================================
// R6 k_ln: tile [512 c][64 (b,p) cols] from RT (256-B runs per c-plane), LN over c in
// LDS, write OUT rows contiguously. LDS layout S[col][c] so the OUT pass reads 8
// consecutive f32x4 per thread (8 lanes/row x 8 rows per instr, ~2-way banks).
// =====================================================================================
template<int HALF>
__global__ __launch_bounds__(1024, 4) void k_ln_rt(
    const void* __restrict__ RTv, float* __restrict__ OUT,
    const float* __restrict__ G,  const float* __restrict__ Be)
{
    __shared__ float S[64][516];        // 64 cols x 512 c (+4 pad) = 132096 B
    __shared__ float pS[16][64];        // partial sums
    __shared__ float pQ[16][64];        // partial sumsq
    __shared__ float mu_s[64], inv_s[64];
    __shared__ float gS[512], bS[512];

    const int tid = threadIdx.x;
    const int colbase = blockIdx.x * 64;

    if (tid < 512) gS[tid] = G[tid];
    else           bS[tid - 512] = Be[tid - 512];

    // ---- stage RT tile: c = pass*64 + (tid>>4), 16 lanes x 16B cover 64 cols ----
    #pragma unroll
    for (int pass = 0; pass < 8; ++pass) {
        const int cc = pass * 64 + (tid >> 4);
        const int ch = (tid & 15) * 4;
        float v0, v1, v2, v3;
        if constexpr (!HALF) {
            f32x4 v = *(const f32x4*)((const float*)RTv + (size_t)cc * MM + colbase + ch);
            v0 = v[0]; v1 = v[1]; v2 = v[2]; v3 = v[3];
        } else {
            u32x2 v = *(const u32x2*)((const unsigned short*)RTv + (size_t)cc * MM + colbase + ch);
            v0 = h2f((unsigned short)(v[0] & 0xffff)); v1 = h2f((unsigned short)(v[0] >> 16));
            v2 = h2f((unsigned short)(v[1] & 0xffff)); v3 = h2f((unsigned short)(v[1] >> 16));
        }
        S[ch + 0][cc] = v0; S[ch + 1][cc] = v1;
        S[ch + 2][cc] = v2; S[ch + 3][cc] = v3;
    }
    __syncthreads();

    // ---- stats: 16 threads per col, c interleaved by 16 (bank-friendly) ----
    const int col = tid >> 4;
    const int cs  = tid & 15;
    float sum = 0.f, sq = 0.f;
    #pragma unroll
    for (int j = 0; j < 32; ++j) {
        float v = S[col][j * 16 + cs];
        sum += v; sq += v * v;
    }
    pS[cs][col] = sum; pQ[cs][col] = sq;
    __syncthreads();

    if (tid < 64) {
        float s = 0.f, q = 0.f;
        #pragma unroll
        for (int k = 0; k < 16; ++k) { s += pS[k][tid]; q += pQ[k][tid]; }
        const float mu  = s * (1.0f / CC);
        const float var = q * (1.0f / CC) - mu * mu;
        mu_s[tid]  = mu;
        inv_s[tid] = rsqrtf(var + LN_EPS);
    }
    __syncthreads();

    // ---- output: thread (col, hs, pos) writes 8 x f32x4; 128-B runs per instr ----
    const int pos = tid & 7;
    const int hs  = (tid >> 3) & 1;
    const float mu  = mu_s[col];
    const float inv = inv_s[col];
    float* orow = OUT + (size_t)(colbase + col) * CC;
    #pragma unroll
    for (int k = 0; k < 8; ++k) {
        const int cc = hs * 256 + k * 32 + pos * 4;
        f32x4 v = *(const f32x4*)&S[col][cc];
        f32x4 o;
        o[0] = (v[0] - mu) * inv * gS[cc + 0] + bS[cc + 0];
        o[1] = (v[1] - mu) * inv * gS[cc + 1] + bS[cc + 1];
        o[2] = (v[2] - mu) * inv * gS[cc + 2] + bS[cc + 2];
        o[3] = (v[3] - mu) * inv * gS[cc + 3] + bS[cc + 3];
        *(f32x4*)(orow + cc) = o;
    }
}

// =====================================================================================
// Legacy fallback (proven R2 path: 340 us total) if workspace is too small.
// =====================================================================================
__global__ __launch_bounds__(1024) void k_mix_legacy(
    const float* __restrict__ X,  const float* __restrict__ W1,
    const float* __restrict__ B1, const float* __restrict__ W2,
    const float* __restrict__ B2, float* __restrict__ OUT)
{
    __shared__ __align__(16) unsigned short XS[16 * 1160];
    __shared__ __align__(16) unsigned short HS[16 * 1152];
    __shared__ __align__(16) float          RS[16 * 1092];
    __shared__ __align__(16) float          BS[16 * 128];

    const int tid  = threadIdx.x;
    const int lane = tid & 63;
    const int wv   = tid >> 6;
    const int lb   = lane & 15;
    const int lq   = lane >> 4;

    const int gid = blockIdx.x;
    const int cg  = gid & 31;
    const int bt  = gid >> 5;
    const int c0  = cg * 16, b0 = bt * 128;
    const int c   = c0 + wv;

    const float* w1c = W1 + (size_t)c * 4096;
    const float* w2c = W2 + (size_t)c * 4096;
    const int wq = lb * 64 + lq * 8;
    s16x8 w1_0_0 = ldwf(w1c +    0 + wq), w1_0_1 = ldwf(w1c +    0 + wq + 32);
    s16x8 w1_1_0 = ldwf(w1c + 1024 + wq), w1_1_1 = ldwf(w1c + 1024 + wq + 32);
    s16x8 w1_2_0 = ldwf(w1c + 2048 + wq), w1_2_1 = ldwf(w1c + 2048 + wq + 32);
    s16x8 w1_3_0 = ldwf(w1c + 3072 + wq), w1_3_1 = ldwf(w1c + 3072 + wq + 32);
    s16x8 w2_0_0 = ldwf(w2c +    0 + wq), w2_0_1 = ldwf(w2c +    0 + wq + 32);
    s16x8 w2_1_0 = ldwf(w2c + 1024 + wq), w2_1_1 = ldwf(w2c + 1024 + wq + 32);
    s16x8 w2_2_0 = ldwf(w2c + 2048 + wq), w2_2_1 = ldwf(w2c + 2048 + wq + 32);
    s16x8 w2_3_0 = ldwf(w2c + 3072 + wq), w2_3_1 = ldwf(w2c + 3072 + wq + 32);

    BS[wv * 128 +      lane] = B1[c * 64 + lane];
    BS[wv * 128 + 64 + lane] = B2[c * 64 + lane];

    const unsigned short* xp = &XS[wv * 1160];
    unsigned short*       hp = &HS[wv * 1152];

    const int sc4 = tid & 3;
    const int sp2 = (tid >> 2) & 31;
    const int sbo = tid >> 7;

    float4 r0[2], r1[2];
    #pragma unroll
    for (int pass = 0; pass < 2; ++pass) {
        const float* src = X + ((size_t)(b0 + pass * 8 + sbo) * PP + 2 * sp2) * CC
                             + c0 + sc4 * 4;
        r0[pass] = *(const float4*)src;
        r1[pass] = *(const float4*)(src + CC);
    }

    for (int s = 0; s < 8; ++s) {
        const int bb = b0 + s * 16;
        #pragma unroll
        for (int pass = 0; pass < 2; ++pass) {
            int b = pass * 8 + sbo;
            *(unsigned*)&XS[(sc4 * 4 + 0) * 1160 + b * 72 + 2 * sp2] = cvt_pk_bf16(r0[pass].x, r1[pass].x);
            *(unsigned*)&XS[(sc4 * 4 + 1) * 1160 + b * 72 + 2 * sp2] = cvt_pk_bf16(r0[pass].y, r1[pass].y);
            *(unsigned*)&XS[(sc4 * 4 + 2) * 1160 + b * 72 + 2 * sp2] = cvt_pk_bf16(r0[pass].z, r1[pass].z);
            *(unsigned*)&XS[(sc4 * 4 + 3) * 1160 + b * 72 + 2 * sp2] = cvt_pk_bf16(r0[pass].w, r1[pass].w);
        }
        __syncthreads();
        if (s < 7) {
            #pragma unroll
            for (int pass = 0; pass < 2; ++pass) {
                const float* src = X + ((size_t)(bb + 16 + pass * 8 + sbo) * PP + 2 * sp2) * CC
                                     + c0 + sc4 * 4;
                r0[pass] = *(const float4*)src;
                r1[pass] = *(const float4*)(src + CC);
            }
        }
        s16x8 xf0 = *(const s16x8*)(xp + lb * 72 +  0 + lq * 8);
        s16x8 xf1 = *(const s16x8*)(xp + lb * 72 + 32 + lq * 8);
        #define DO1(mt) { \
            float4 bv = *(const float4*)&BS[wv * 128 + mt * 16 + lq * 4]; \
            f32x4 a = {bv.x, bv.y, bv.z, bv.w}; \
            a = __builtin_amdgcn_mfma_f32_16x16x32_bf16(w1_##mt##_0, xf0, a, 0, 0, 0); \
            a = __builtin_amdgcn_mfma_f32_16x16x32_bf16(w1_##mt##_1, xf1, a, 0, 0, 0); \
            u32x2 hpk; \
            hpk[0] = cvt_pk_bf16(gelu_t(a[0]), gelu_t(a[1])); \
            hpk[1] = cvt_pk_bf16(gelu_t(a[2]), gelu_t(a[3])); \
            *(u32x2*)(hp + lb * 72 + mt * 16 + lq * 4) = hpk; }
        DO1(0) DO1(1) DO1(2) DO1(3)
        #undef DO1
        asm volatile("s_waitcnt lgkmcnt(0)" ::: "memory");
        s16x8 hf0 = *(const s16x8*)(hp + lb * 72 +  0 + lq * 8);
        s16x8 hf1 = *(const s16x8*)(hp + lb * 72 + 32 + lq * 8);
        #define DO2(mt) { \
            float4 bv = *(const float4*)&BS[wv * 128 + 64 + mt * 16 + lq * 4]; \
            f32x4 a = {bv.x, bv.y, bv.z, bv.w}; \
            a = __builtin_amdgcn_mfma_f32_16x16x32_bf16(w2_##mt##_0, hf0, a, 0, 0, 0); \
            a = __builtin_amdgcn_mfma_f32_16x16x32_bf16(w2_##mt##_1, hf1, a, 0, 0, 0); \
            u32x2 xv = *(const u32x2*)(xp + lb * 72 + mt * 16 + lq * 4); \
            a[0] += bflo(xv[0]); a[1] += bfhi(xv[0]); \
            a[2] += bflo(xv[1]); a[3] += bfhi(xv[1]); \
            *(f32x4*)&RS[lb * 1092 + wv * 68 + mt * 16 + lq * 4] = a; }
        DO2(0) DO2(1) DO2(2) DO2(3)
        #undef DO2
        __syncthreads();
        #pragma unroll
        for (int it = 0; it < 4; ++it) {
            int fi = it * 1024 + tid;
            int c4 = fi & 3, q = (fi >> 2) & 63, b = fi >> 8;
            const float* rp = &RS[b * 1092 + c4 * 4 * 68 + q];
            float4 v = { rp[0], rp[68], rp[136], rp[204] };
            *(float4*)(OUT + ((size_t)(bb + b) * PP + q) * CC + c0 + c4 * 4) = v;
        }
    }
}

__global__ __launch_bounds__(256) void k_ln_legacy(
    float* __restrict__ OUT, const float* __restrict__ G, const float* __restrict__ Be)
{
    const int lane = threadIdx.x & 63;
    const int m    = blockIdx.x * 4 + (threadIdx.x >> 6);
    float4* row = (float4*)(OUT + (size_t)m * CC);
    float4 v0 = row[lane], v1 = row[lane + 64];
    float s = (v0.x + v0.y) + (v0.z + v0.w) + (v1.x + v1.y) + (v1.z + v1.w);
    float q = (v0.x * v0.x + v0.y * v0.y) + (v0.z * v0.z + v0.w * v0.w)
            + (v1.x * v1.x + v1.y * v1.y) + (v1.z * v1.z + v1.w * v1.w);
    #pragma unroll
    for (int o = 32; o >= 1; o >>= 1) {
        s += __shfl_xor(s, o, 64);
        q += __shfl_xor(q, o, 64);
    }
    const float mu  = s * (1.0f / CC);
    const float var = q * (1.0f / CC) - mu * mu;
    const float inv = rsqrtf(var + LN_EPS);
    const float4 g0 = ((const float4*)G)[lane],  g1 = ((const float4*)G)[lane + 64];
    const float4 e0 = ((const float4*)Be)[lane], e1 = ((const float4*)Be)[lane + 64];
    v0.x = (v0.x - mu) * inv * g0.x + e0.x;  v0.y = (v0.y - mu) * inv * g0.y + e0.y;
    v0.z = (v0.z - mu) * inv * g0.z + e0.z;  v0.w = (v0.w - mu) * inv * g0.w + e0.w;
    v1.x = (v1.x - mu) * inv * g1.x + e1.x;  v1.y = (v1.y - mu) * inv * g1.y + e1.y;
    v1.z = (v1.z - mu) * inv * g1.z + e1.z;  v1.w = (v1.w - mu) * inv * g1.w + e1.w;
    row[lane] = v0; row[lane + 64] = v1;
}

extern "C" void kernel_launch(void* const* d_in, const int* in_sizes, int n_in,
                              void* d_out, int out_size, void* d_ws, size_t ws_size,
                              hipStream_t stream) {
    const float* X  = (const float*)d_in[0];
    const float* W1 = (const float*)d_in[1];
    const float* B1 = (const float*)d_in[2];
    const float* W2 = (const float*)d_in[3];
    const float* B2 = (const float*)d_in[4];
    const float* G  = (const float*)d_in[5];
    const float* Be = (const float*)d_in[6];
    float* OUT = (float*)d_out;

    const size_t need32 = (size_t)CC * MM * sizeof(float);          // 134 MB
    const size_t need16 = (size_t)CC * MM * sizeof(unsigned short); //  67 MB

    if (d_ws && ws_size >= need32) {
        k_mix_rt<0><<<256, 1024, 0, stream>>>(X, W1, B1, W2, B2, d_ws);
        k_ln_rt<0><<<MM / 64, 1024, 0, stream>>>(d_ws, OUT, G, Be);
    } else if (d_ws && ws_size >= need16) {
        k_mix_rt<1><<<256, 1024, 0, stream>>>(X, W1, B1, W2, B2, d_ws);
        k_ln_rt<1><<<MM / 64, 1024, 0, stream>>>(d_ws, OUT, G, Be);
    } else {
        k_mix_legacy<<<256, 1024, 0, stream>>>(X, W1, B1, W2, B2, OUT);
        k_ln_legacy<<<MM / 4, 256, 0, stream>>>(OUT, G, Be);
    }
}